// Round 1
// 1337.417 us; speedup vs baseline: 1.7647x; 1.7647x over previous
//
#include <hip/hip_runtime.h>
#include <hip/hip_bf16.h>

typedef __attribute__((ext_vector_type(8))) short bf16x8;
typedef __attribute__((ext_vector_type(4))) float f32x4;

#define MB ((size_t)1024 * 1024)

// ---------------- transpose + fp32->bf16 convert ----------------
// W: [K][N] fp32 row-major  ->  Wt: [N][K] bf16 row-major. K,N multiples of 32.
__global__ __launch_bounds__(256)
void transpose_convert(const float* __restrict__ W, __hip_bfloat16* __restrict__ Wt,
                       int K, int N) {
  __shared__ float tile[32][33];
  int n0 = blockIdx.x * 32;
  int k0 = blockIdx.y * 32;
  int tx = threadIdx.x;   // 0..31
  int ty = threadIdx.y;   // 0..7
#pragma unroll
  for (int i = 0; i < 4; i++) {
    tile[ty + i * 8][tx] = W[(size_t)(k0 + ty + i * 8) * N + n0 + tx];
  }
  __syncthreads();
#pragma unroll
  for (int i = 0; i < 4; i++) {
    Wt[(size_t)(n0 + ty + i * 8) * K + k0 + tx] = __float2bfloat16(tile[tx][ty + i * 8]);
  }
}

// ---------------- embedding gather -> bf16 ----------------
__global__ __launch_bounds__(256)
void gather_embed(const int* __restrict__ ids, const float* __restrict__ emb,
                  __hip_bfloat16* __restrict__ out, int ME, int E) {
  int gid = blockIdx.x * 256 + threadIdx.x;
  if (gid >= ME) return;
  int m = gid / E;
  int e = gid - m * E;
  out[gid] = __float2bfloat16(emb[(size_t)ids[m] * E + e]);
}

// ---------------- bf16 GEMM, B pre-transposed ----------------
// C[m][n] = (sum_k A[m][k]*Bt[n][k] + bias[n]) * (1 + strength*(gains[m]-1))
// A: [M][K] bf16 row-major, Bt: [N][K] bf16 row-major, C: [M][N] fp32.
// M,N multiples of 128; K multiple of 32.
__global__ __launch_bounds__(256, 2)
void gemm_bt(const short* __restrict__ A, const short* __restrict__ Bt,
             const float* __restrict__ bias, const float* __restrict__ gains,
             float strength, float* __restrict__ C, int M, int N, int K) {
  // +8 pad: row stride 80 B = 5*16 B -> b128 ops stay 16B-aligned; bank stride
  // 20 -> 2-way aliasing on frag reads (free per m136).
  __shared__ short As[128][40];
  __shared__ short Bs[128][40];
  int tid = threadIdx.x;
  int wave = tid >> 6, lane = tid & 63;
  int bm = blockIdx.y * 128, bn = blockIdx.x * 128;
  int wr = (wave >> 1) * 64, wc = (wave & 1) * 64;

  f32x4 acc[4][4] = {};

  int fm = lane & 15;          // fragment row within 16
  int fk = (lane >> 4) * 8;    // fragment k offset (quad*8)

  for (int k0 = 0; k0 < K; k0 += 32) {
    // stage 128x32 A and Bt tiles: 512 16B-chunks each, 2 per thread
#pragma unroll
    for (int i = 0; i < 2; i++) {
      int c = tid + i * 256;
      int r = c >> 2;            // tile row 0..127
      int kk = (c & 3) * 8;      // k offset 0/8/16/24
      *reinterpret_cast<bf16x8*>(&As[r][kk]) =
          *reinterpret_cast<const bf16x8*>(&A[(size_t)(bm + r) * K + k0 + kk]);
      *reinterpret_cast<bf16x8*>(&Bs[r][kk]) =
          *reinterpret_cast<const bf16x8*>(&Bt[(size_t)(bn + r) * K + k0 + kk]);
    }
    __syncthreads();
    bf16x8 af[4], bfr[4];
#pragma unroll
    for (int i = 0; i < 4; i++) {
      af[i]  = *reinterpret_cast<const bf16x8*>(&As[wr + i * 16 + fm][fk]);
      bfr[i] = *reinterpret_cast<const bf16x8*>(&Bs[wc + i * 16 + fm][fk]);
    }
#pragma unroll
    for (int i = 0; i < 4; i++)
#pragma unroll
      for (int j = 0; j < 4; j++)
        acc[i][j] = __builtin_amdgcn_mfma_f32_16x16x32_bf16(af[i], bfr[j], acc[i][j], 0, 0, 0);
    __syncthreads();
  }

  // epilogue: C/D layout col=lane&15, row=(lane>>4)*4+reg (m89/m91-verified)
  int col0 = lane & 15;
  int row0 = (lane >> 4) * 4;
#pragma unroll
  for (int i = 0; i < 4; i++) {
#pragma unroll
    for (int r = 0; r < 4; r++) {
      int m = bm + wr + i * 16 + row0 + r;
      float mod = 1.0f + strength * (gains[m] - 1.0f);
#pragma unroll
      for (int j = 0; j < 4; j++) {
        int n = bn + wc + j * 16 + col0;
        C[(size_t)m * N + n] = (acc[i][j][r] + bias[n]) * mod;
      }
    }
  }
}

// ---------------- GIF leaky-integrate soft-spike scan ----------------
// cur: [B][S][D] fp32 (already modulated+biased). spikes out as bf16 [B][S][D].
// Latency-bound structure (only B*D independent channels). Fix: register
// double-buffer of CH=32 future inputs per thread -- the loads are independent
// of the recurrence state v, so chunk i+1's 32 loads are in flight while
// chunk i's ~800 cycles of VALU+transcendental run. Named bufA/bufB with
// fully-unrolled static indices (runtime-indexed arrays spill to scratch).
// 64-thread blocks spread the few waves over more CUs.
__global__ __launch_bounds__(64)
void gif_scan(const float* __restrict__ cur, __hip_bfloat16* __restrict__ spikes,
              int Bb, int S, int D) {
  const int CH = 32;   // S=2048 -> 64 chunks (even), depth-2 ping-pong
  int ch = blockIdx.x * 64 + threadIdx.x;
  if (ch >= Bb * D) return;
  int b = ch / D;
  int d = ch - b * D;
  const float* c = cur + (size_t)b * S * D + d;
  __hip_bfloat16* sp = spikes + (size_t)b * S * D + d;

  float bufA[CH], bufB[CH];
#pragma unroll
  for (int j = 0; j < CH; j++) bufA[j] = c[(size_t)j * D];

  float v = 0.0f;
  const int nc = S / CH;     // 64
  for (int i = 0; i < nc; i += 2) {
    // prefetch chunk i+1 into bufB (always exists: nc even, i+1 <= nc-1)
#pragma unroll
    for (int j = 0; j < CH; j++) bufB[j] = c[(size_t)((i + 1) * CH + j) * D];
    // compute chunk i from bufA
#pragma unroll
    for (int j = 0; j < CH; j++) {
      v = 0.9f * v + bufA[j];
      float sig = 1.0f / (1.0f + __expf(-4.0f * (v - 1.0f)));
      v -= sig;           // soft reset, THETA=1
      sp[(size_t)(i * CH + j) * D] = __float2bfloat16(sig);
    }
    // prefetch chunk i+2 into bufA
    if (i + 2 < nc) {
#pragma unroll
      for (int j = 0; j < CH; j++) bufA[j] = c[(size_t)((i + 2) * CH + j) * D];
    }
    // compute chunk i+1 from bufB
#pragma unroll
    for (int j = 0; j < CH; j++) {
      v = 0.9f * v + bufB[j];
      float sig = 1.0f / (1.0f + __expf(-4.0f * (v - 1.0f)));
      v -= sig;
      sp[(size_t)((i + 1) * CH + j) * D] = __float2bfloat16(sig);
    }
  }
}

extern "C" void kernel_launch(void* const* d_in, const int* in_sizes, int n_in,
                              void* d_out, int out_size, void* d_ws, size_t ws_size,
                              hipStream_t stream) {
  const int B = 2, S = 2048, V = 32000, E = 1024, H = 2048;
  const int M = B * S;  // 4096

  const int*   ids   = (const int*)d_in[0];    // (B,S)
  const float* gains = (const float*)d_in[1];  // (B,S)
  const float* emb   = (const float*)d_in[2];  // (V,E)
  const float* encW  = (const float*)d_in[3];  // (E,H)
  const float* encb  = (const float*)d_in[4];  // (H)
  const float* decW  = (const float*)d_in[5];  // (H,E)
  const float* decb  = (const float*)d_in[6];  // (E)
  const float* outW  = (const float*)d_in[7];  // (E,V)
  const float* outb  = (const float*)d_in[8];  // (V)
  float* out = (float*)d_out;                  // (M,V)

  char* ws = (char*)d_ws;
  // Aliased layout (88 MB total):
  //  outWt (62.5 MB @16MB) overlays emb/cur_enc/spikes_enc/cur_dec, all dead
  //  by the time the out_W transpose runs.
  __hip_bfloat16* encWt  = (__hip_bfloat16*)(ws + 0);        // 4 MB  [H][E]
  __hip_bfloat16* decWt  = (__hip_bfloat16*)(ws + 4 * MB);   // 4 MB  [E][H]
  __hip_bfloat16* spkdec = (__hip_bfloat16*)(ws + 8 * MB);   // 8 MB  [M][E]
  __hip_bfloat16* embB   = (__hip_bfloat16*)(ws + 16 * MB);  // 8 MB  [M][E]
  float*          curenc = (float*)(ws + 24 * MB);           // 32 MB [M][H]
  __hip_bfloat16* spkenc = (__hip_bfloat16*)(ws + 56 * MB);  // 16 MB [M][H]
  float*          curdec = (float*)(ws + 72 * MB);           // 16 MB [M][E]
  __hip_bfloat16* outWt  = (__hip_bfloat16*)(ws + 16 * MB);  // 62.5 MB [V][E]

  dim3 b32x8(32, 8);

  // 1. enc_W [E][H] -> encWt [H][E]
  transpose_convert<<<dim3(H / 32, E / 32), b32x8, 0, stream>>>(encW, encWt, E, H);
  // 2. embedding gather -> bf16
  gather_embed<<<(M * E + 255) / 256, 256, 0, stream>>>(ids, emb, embB, M * E, E);
  // 3. GEMM1: cur_enc = (embB @ enc_W + enc_b) * mod(0.3)
  gemm_bt<<<dim3(H / 128, M / 128), 256, 0, stream>>>(
      (const short*)embB, (const short*)encWt, encb, gains, 0.3f, curenc, M, H, E);
  // 4. GIF scan 1 -> spikes_enc (bf16)
  gif_scan<<<(B * H + 63) / 64, 64, 0, stream>>>(curenc, spkenc, B, S, H);
  // 5. dec_W [H][E] -> decWt [E][H]
  transpose_convert<<<dim3(E / 32, H / 32), b32x8, 0, stream>>>(decW, decWt, H, E);
  // 6. GEMM2: cur_dec = (spikes_enc @ dec_W + dec_b) * mod(0.2)
  gemm_bt<<<dim3(E / 128, M / 128), 256, 0, stream>>>(
      (const short*)spkenc, (const short*)decWt, decb, gains, 0.2f, curdec, M, E, H);
  // 7. GIF scan 2 -> spikes_dec (bf16)
  gif_scan<<<(B * E + 63) / 64, 64, 0, stream>>>(curdec, spkdec, B, S, E);
  // 8. out_W [E][V] -> outWt [V][E]
  transpose_convert<<<dim3(V / 32, E / 32), b32x8, 0, stream>>>(outW, outWt, E, V);
  // 9. GEMM3: logits = spikes_dec @ out_W + out_b  (strength 0 -> mod=1)
  gemm_bt<<<dim3(V / 128, M / 128), 256, 0, stream>>>(
      (const short*)spkdec, (const short*)outWt, outb, gains, 0.0f, out, M, V, E);
}